// Round 4
// baseline (37.207 us; speedup 1.0000x reference)
//
#include <hip/hip_runtime.h>

#define CDIM 128
#define HDIM 128
#define MT   128    // rows per node block (4 waves x 32 rows)
#define LDP  136    // hs row stride in shorts (272 B, 16B-aligned)
#define LIM  40960  // nodes cached in edge LDS (x4 B = 163840 B = full 160 KiB)

typedef short bf16x8 __attribute__((ext_vector_type(8)));
typedef float f32x16 __attribute__((ext_vector_type(16)));

// fp32 -> bf16 bits, round-to-nearest-even
static __device__ __forceinline__ short f2bf(float f) {
    union { float f; unsigned u; } v; v.f = f;
    unsigned r = v.u + 0x7FFFu + ((v.u >> 16) & 1u);
    return (short)(r >> 16);
}

// ---------------------------------------------------------------------------
// Prologue: emit W1, W2 in fragment-linear bf16 layout for 32x32x16 MFMA:
// wf[((ct*8+ks)*64 + lane)*8 + j] = bf16(W[k][n]),
//   k = ks*16 + (lane>>5)*8 + j,  n = ct*32 + (lane&31).
// B-reads in the node kernel become lane-linear ds_read_b128 (0 conflicts).
// ---------------------------------------------------------------------------
__global__ __launch_bounds__(256) void prep_kernel(
    const float* __restrict__ W1, const float* __restrict__ W2,
    short* __restrict__ wf1, short* __restrict__ wf2)
{
    int id = blockIdx.x * 256 + threadIdx.x;   // 0..32767
    const float* src = (id < 16384) ? W1 : W2;
    short* dst = (id < 16384) ? wf1 : wf2;
    int rem = id & 16383;
    int j  = rem & 7;
    int l  = (rem >> 3) & 63;
    int ks = (rem >> 9) & 7;
    int ct = rem >> 12;
    int k = ks * 16 + (l >> 5) * 8 + j;
    int n = ct * 32 + (l & 31);
    dst[rem] = f2bf(src[k * HDIM + n]);
}

// ---------------------------------------------------------------------------
// Node pass: h2 = relu(relu(x@W1+b1)@W2+b2); tab[n] = pack(bf16(h2.Wq), bf16(h2.Wk))
// 256 thr (4 waves), 128 rows/block, mfma_f32_32x32x16_bf16.
// A: row = lane&31, k = ks*16 + 8*(lane>>5) + j  (A and B share the k-map).
// D: col = lane&31, row = (r&3) + 8*(r>>2) + 4*(lane>>5)   [m74/m101 verified]
// ---------------------------------------------------------------------------
__global__ __launch_bounds__(256) void node_mfma(
    const float* __restrict__ x,
    const short* __restrict__ wf1, const float* __restrict__ b1,
    const short* __restrict__ wf2, const float* __restrict__ b2,
    const float* __restrict__ We,
    unsigned* __restrict__ tab, int N)
{
    __shared__ __align__(16) short wf[16384];     // fragment-linear W (one layer)
    __shared__ __align__(16) short hs[MT][LDP];   // h1 bf16, block rows

    const int tid = threadIdx.x;
    const int w  = tid >> 6;
    const int l  = tid & 63;
    const int lr = l & 31;          // A-row / B-col / D-col
    const int h  = l >> 5;          // k-half
    const int rowg0 = blockIdx.x * MT + w * 32;

    // ---- stage wf1 via async global->LDS DMA (16 B/lane, wave-uniform dest) ----
#pragma unroll
    for (int t = 0; t < 8; t++) {
        int c = (t * 4 + w) * 64;   // uint4 chunk base (64 uint4 per wave-iter)
        __builtin_amdgcn_global_load_lds(
            (const __attribute__((address_space(1))) void*)((const uint4*)wf1 + c + l),
            (__attribute__((address_space(3))) void*)((char*)wf + (size_t)c * 16),
            16, 0, 0);
    }
    __syncthreads();

    const f32x16 zz = {0.f,0.f,0.f,0.f,0.f,0.f,0.f,0.f,0.f,0.f,0.f,0.f,0.f,0.f,0.f,0.f};
    f32x16 acc[4];
#pragma unroll
    for (int ct = 0; ct < 4; ct++) acc[ct] = zz;

    // ---- layer 1: A from global x (fp32 -> bf16), B from LDS (lane-linear) ----
    const int arow = rowg0 + lr;
    const float* xbase = &x[arow * CDIM + h * 8];
#pragma unroll
    for (int ks = 0; ks < 8; ks++) {
        bf16x8 a;
        if (arow < N) {
            float4 v0 = *(const float4*)(xbase + ks * 16);
            float4 v1 = *(const float4*)(xbase + ks * 16 + 4);
            a[0] = f2bf(v0.x); a[1] = f2bf(v0.y); a[2] = f2bf(v0.z); a[3] = f2bf(v0.w);
            a[4] = f2bf(v1.x); a[5] = f2bf(v1.y); a[6] = f2bf(v1.z); a[7] = f2bf(v1.w);
        } else {
            a = (bf16x8){0, 0, 0, 0, 0, 0, 0, 0};
        }
#pragma unroll
        for (int ct = 0; ct < 4; ct++) {
            bf16x8 b = *(const bf16x8*)&wf[((ct * 8 + ks) * 64 + l) * 8];
            acc[ct] = __builtin_amdgcn_mfma_f32_32x32x16_bf16(a, b, acc[ct], 0, 0, 0);
        }
    }

    // ---- h1 = relu(acc + b1) -> hs ----
#pragma unroll
    for (int ct = 0; ct < 4; ct++) {
        const int col = ct * 32 + lr;
        const float bb = b1[col];
#pragma unroll
        for (int r = 0; r < 16; r++) {
            int row = w * 32 + (r & 3) + 8 * (r >> 2) + 4 * h;
            hs[row][col] = f2bf(fmaxf(acc[ct][r] + bb, 0.f));
        }
        acc[ct] = zz;
    }
    __syncthreads();   // all waves done reading wf(W1), hs visible to self

    // ---- restage wf = wf2 ----
#pragma unroll
    for (int t = 0; t < 8; t++) {
        int c = (t * 4 + w) * 64;
        __builtin_amdgcn_global_load_lds(
            (const __attribute__((address_space(1))) void*)((const uint4*)wf2 + c + l),
            (__attribute__((address_space(3))) void*)((char*)wf + (size_t)c * 16),
            16, 0, 0);
    }
    __syncthreads();

    // ---- layer 2: A from hs, B from LDS ----
#pragma unroll
    for (int ks = 0; ks < 8; ks++) {
        bf16x8 a = *(const bf16x8*)&hs[w * 32 + lr][ks * 16 + h * 8];
#pragma unroll
        for (int ct = 0; ct < 4; ct++) {
            bf16x8 b = *(const bf16x8*)&wf[((ct * 8 + ks) * 64 + l) * 8];
            acc[ct] = __builtin_amdgcn_mfma_f32_32x32x16_bf16(a, b, acc[ct], 0, 0, 0);
        }
    }

    // ---- epilogue: pq = relu(h2).Wq, pk = relu(h2).Wk; reduce across 32 cols ----
    float pq[16], pk[16];
#pragma unroll
    for (int r = 0; r < 16; r++) { pq[r] = 0.f; pk[r] = 0.f; }
#pragma unroll
    for (int ct = 0; ct < 4; ct++) {
        const int col = ct * 32 + lr;
        const float bb = b2[col];
        const float wq = We[col];
        const float wk = We[HDIM + col];
#pragma unroll
        for (int r = 0; r < 16; r++) {
            float hv = fmaxf(acc[ct][r] + bb, 0.f);
            pq[r] = fmaf(hv, wq, pq[r]);
            pk[r] = fmaf(hv, wk, pk[r]);
        }
    }
#pragma unroll
    for (int r = 0; r < 16; r++) {
#pragma unroll
        for (int s = 1; s < 32; s <<= 1) {
            pq[r] += __shfl_xor(pq[r], s, 64);
            pk[r] += __shfl_xor(pk[r], s, 64);
        }
    }
    if (lr == 0) {
#pragma unroll
        for (int r = 0; r < 16; r++) {
            int n = rowg0 + (r & 3) + 8 * (r >> 2) + 4 * h;
            if (n < N) {
                tab[n] = (unsigned)(unsigned short)f2bf(pq[r])
                       | ((unsigned)(unsigned short)f2bf(pk[r]) << 16);
            }
        }
    }
}

// ---------------------------------------------------------------------------
// Edge pass. Phase 0: issue async LDS staging of the score table.
// Phase A (overlapped with DMA): write float casts of edge_index_neg.
// Phase B (after barrier drains vmcnt): gather scores, write pos/neg scores.
// ---------------------------------------------------------------------------
__global__ __launch_bounds__(1024) void edge_kernel(
    const int* __restrict__ eip, const int* __restrict__ ein,
    const unsigned* __restrict__ tab, const float* __restrict__ be_p,
    float* __restrict__ out, int E)
{
    __shared__ __align__(16) unsigned lt[LIM];   // 163840 B
    const int tid = threadIdx.x;
    const int wv = tid >> 6, ln = tid & 63;

    // ---- issue staging DMA: LIM/4 uint4 = 10240, 16 waves x 10 iters x 64 lanes ----
    const uint4* tg4 = (const uint4*)tab;
#pragma unroll
    for (int t = 0; t < LIM / 4 / 1024; t++) {
        int c = (t * 16 + wv) * 64;              // uint4 chunk base
        __builtin_amdgcn_global_load_lds(
            (const __attribute__((address_space(1))) void*)(tg4 + c + ln),
            (__attribute__((address_space(3))) void*)((char*)lt + (size_t)c * 16),
            16, 0, 0);
    }
    __builtin_amdgcn_sched_barrier(0);   // keep DMA issue ahead of phase A

    const int chunk = (E + gridDim.x - 1) / gridDim.x;
    const int estart = blockIdx.x * chunk;
    const int eend = min(E, estart + chunk);

    // ---- phase A: table-independent output (hides DMA latency) ----
    for (int e = estart + tid; e < eend; e += 1024) {
        int ns = ein[e], nd = ein[E + e];
        out[2 * E + e] = (float)ns;
        out[3 * E + e] = (float)nd;
    }
    __syncthreads();   // s_waitcnt vmcnt(0) lgkmcnt(0) + barrier: staging done

    // ---- phase B: score gathers (LDS for n < LIM, L2 residual otherwise) ----
    const float be = be_p[0];
    for (int e = estart + tid; e < eend; e += 1024) {
        int ps = eip[e], pd = eip[E + e];
        int ns = ein[e], nd = ein[E + e];
        unsigned ups = (ps < LIM) ? lt[ps] : tab[ps];
        unsigned upd = (pd < LIM) ? lt[pd] : tab[pd];
        unsigned uns = (ns < LIM) ? lt[ns] : tab[ns];
        unsigned und = (nd < LIM) ? lt[nd] : tab[nd];
        out[e]     = __uint_as_float(ups << 16) + __uint_as_float(upd & 0xFFFF0000u) + be;
        out[E + e] = __uint_as_float(uns << 16) + __uint_as_float(und & 0xFFFF0000u) + be;
    }
}

extern "C" void kernel_launch(void* const* d_in, const int* in_sizes, int n_in,
                              void* d_out, int out_size, void* d_ws, size_t ws_size,
                              hipStream_t stream) {
    const float* x   = (const float*)d_in[0];
    const int*   eip = (const int*)d_in[1];
    const int*   ein = (const int*)d_in[2];
    // d_in[3] = batch (unused)
    const float* W1  = (const float*)d_in[4];
    const float* b1  = (const float*)d_in[5];
    const float* W2  = (const float*)d_in[6];
    const float* b2  = (const float*)d_in[7];
    const float* We  = (const float*)d_in[8];
    const float* be  = (const float*)d_in[9];

    const int N = in_sizes[0] / CDIM;
    const int E = in_sizes[1] / 2;

    // workspace: [0, 200704) packed bf16x2 score table; then fragment-linear W
    char* ws = (char*)d_ws;
    unsigned* tab = (unsigned*)ws;                   // N*4 B
    short*    wf1 = (short*)(ws + 200704);           // 32768 B
    short*    wf2 = (short*)(ws + 200704 + 32768);   // 32768 B

    prep_kernel<<<128, 256, 0, stream>>>(W1, W2, wf1, wf2);
    node_mfma<<<(N + MT - 1) / MT, 256, 0, stream>>>(x, wf1, b1, wf2, b2, We, tab, N);
    edge_kernel<<<256, 1024, 0, stream>>>(eip, ein, tab, be, (float*)d_out, E);
}

// Round 5
// 32.691 us; speedup vs baseline: 1.1381x; 1.1381x over previous
//
#include <hip/hip_runtime.h>

#define CDIM 128
#define HDIM 128
#define LIM  40960   // nodes cached in edge LDS (x4 B = 163840 B = full 160 KiB)

typedef short bf16x8 __attribute__((ext_vector_type(8)));
typedef float f32x16 __attribute__((ext_vector_type(16)));

// fp32 -> bf16 bits, round-to-nearest-even
static __device__ __forceinline__ short f2bf(float f) {
    union { float f; unsigned u; } v; v.f = f;
    unsigned r = v.u + 0x7FFFu + ((v.u >> 16) & 1u);
    return (short)(r >> 16);
}
static __device__ __forceinline__ unsigned pack2(float a, float b) {
    return (unsigned)(unsigned short)f2bf(a) | ((unsigned)(unsigned short)f2bf(b) << 16);
}

// ---------------------------------------------------------------------------
// Prologue: fragment-linear bf16 weights for 32x32x16 MFMA (operand lane map:
// idx = lane&31, k = ks*16 + 8*(lane>>5) + j):
//   wf[((ct*8+ks)*64 + lane)*8 + j] = bf16(W[k][n]), k=ks*16+8*(lane>>5)+j,
//   n = ct*32 + (lane&31).
// ---------------------------------------------------------------------------
__global__ __launch_bounds__(256) void prep_kernel(
    const float* __restrict__ W1, const float* __restrict__ W2,
    short* __restrict__ wf1, short* __restrict__ wf2)
{
    int id = blockIdx.x * 256 + threadIdx.x;   // 0..32767
    const float* src = (id < 16384) ? W1 : W2;
    short* dst = (id < 16384) ? wf1 : wf2;
    int rem = id & 16383;
    int j  = rem & 7;
    int l  = (rem >> 3) & 63;
    int ks = (rem >> 9) & 7;
    int ct = rem >> 12;
    int k = ks * 16 + (l >> 5) * 8 + j;
    int n = ct * 32 + (l & 31);
    dst[rem] = f2bf(src[k * HDIM + n]);
}

// ---------------------------------------------------------------------------
// Node pass, fully in-register chaining (transposed compute):
//   layer 1: D1 = W1^T x^T  -> D1 col (lane&31) = node, rows = n1 features
//   lane packs its 64 h1 features (bf16 pairs P); partner half via shfl_xor 32
//   layer 2: B2 fragment assembled in-register; D2 col = node, rows = n2
//   epilogue: per-lane partial dot with Wq/Wk, one shfl_xor(32), lanes<32 write.
// 256 thr (4 waves), 128 nodes/block, both W layers staged once (64 KB LDS).
// ---------------------------------------------------------------------------
__global__ __launch_bounds__(256, 2) void node_mfma(
    const float* __restrict__ x,
    const short* __restrict__ wf1, const float* __restrict__ b1,
    const short* __restrict__ wf2, const float* __restrict__ b2,
    const float* __restrict__ We,
    unsigned* __restrict__ tab, int N)
{
    __shared__ __align__(16) short wfA[2][16384];  // 64 KB: both layers
    __shared__ __align__(16) float cv[512];        // b1 | b2 | Wq | Wk

    const int tid = threadIdx.x;
    const int w   = tid >> 6;
    const int l   = tid & 63;
    const int col = l & 31;          // node slot within wave tile
    const int hi  = l >> 5;
    const int node = blockIdx.x * 128 + w * 32 + col;

    // ---- stage both weight layers: 4096 uint4 via async DMA (16B/lane) ----
#pragma unroll
    for (int t = 0; t < 16; t++) {
        int c = (t * 4 + w) * 64;   // uint4 index into combined 4096 (wave-uniform)
        const uint4* src = (c < 2048) ? ((const uint4*)wf1 + c)
                                      : ((const uint4*)wf2 + (c - 2048));
        __builtin_amdgcn_global_load_lds(
            (const __attribute__((address_space(1))) void*)(src + l),
            (__attribute__((address_space(3))) void*)((char*)wfA + (size_t)c * 16),
            16, 0, 0);
    }
    for (int i = tid; i < 512; i += 256)
        cv[i] = (i < 128) ? b1[i] : (i < 256) ? b2[i - 128] : We[i - 256];
    __syncthreads();

    const f32x16 zz = {0.f,0.f,0.f,0.f,0.f,0.f,0.f,0.f,0.f,0.f,0.f,0.f,0.f,0.f,0.f,0.f};

    // ---- layer 1: A = W1-frag (LDS, lane-linear), B = x^T-frag (global) ----
    const int nclamp = (node < N) ? node : (N - 1);
    const float* xb = &x[(size_t)nclamp * CDIM + hi * 8];
    f32x16 acc[4];
#pragma unroll
    for (int ct = 0; ct < 4; ct++) acc[ct] = zz;

#pragma unroll
    for (int ks = 0; ks < 8; ks++) {
        float4 v0 = *(const float4*)(xb + ks * 16);
        float4 v1 = *(const float4*)(xb + ks * 16 + 4);
        bf16x8 a;
        a[0] = f2bf(v0.x); a[1] = f2bf(v0.y); a[2] = f2bf(v0.z); a[3] = f2bf(v0.w);
        a[4] = f2bf(v1.x); a[5] = f2bf(v1.y); a[6] = f2bf(v1.z); a[7] = f2bf(v1.w);
#pragma unroll
        for (int ct = 0; ct < 4; ct++) {
            bf16x8 wfrag = *(const bf16x8*)&wfA[0][((ct * 8 + ks) * 64 + l) * 8];
            acc[ct] = __builtin_amdgcn_mfma_f32_32x32x16_bf16(wfrag, a, acc[ct], 0, 0, 0);
        }
    }

    // ---- h1 = relu(D1 + b1): pack own 64 features as bf16 pairs ----
    // lane's n1 = 32ct + 8g + 4hi + i   (i = reg&3, g = reg>>2)
    unsigned P[4][4][2], Q[4][4][2];
#pragma unroll
    for (int ct = 0; ct < 4; ct++) {
#pragma unroll
        for (int g = 0; g < 4; g++) {
            float4 bv = *(const float4*)&cv[32 * ct + 8 * g + 4 * hi];
            float h0 = fmaxf(acc[ct][4 * g + 0] + bv.x, 0.f);
            float h1v = fmaxf(acc[ct][4 * g + 1] + bv.y, 0.f);
            float h2v = fmaxf(acc[ct][4 * g + 2] + bv.z, 0.f);
            float h3v = fmaxf(acc[ct][4 * g + 3] + bv.w, 0.f);
            P[ct][g][0] = pack2(h0, h1v);
            P[ct][g][1] = pack2(h2v, h3v);
        }
    }
#pragma unroll
    for (int ct = 0; ct < 4; ct++)
#pragma unroll
        for (int g = 0; g < 4; g++)
#pragma unroll
            for (int p = 0; p < 2; p++)
                Q[ct][g][p] = (unsigned)__shfl_xor((int)P[ct][g][p], 32, 64);

    // ---- layer 2: B2 frag in-register; A = W2-frag from LDS ----
    f32x16 acc2[4];
#pragma unroll
    for (int ct = 0; ct < 4; ct++) acc2[ct] = zz;

#pragma unroll
    for (int ks2 = 0; ks2 < 8; ks2++) {
        const int c  = ks2 >> 1;
        const int s2 = (ks2 & 1) * 2;
        union { bf16x8 v; unsigned u[4]; } bb;
        bb.u[0] = hi ? Q[c][s2 + 1][0] : P[c][s2][0];
        bb.u[1] = hi ? Q[c][s2 + 1][1] : P[c][s2][1];
        bb.u[2] = hi ? P[c][s2 + 1][0] : Q[c][s2][0];
        bb.u[3] = hi ? P[c][s2 + 1][1] : Q[c][s2][1];
#pragma unroll
        for (int ct = 0; ct < 4; ct++) {
            bf16x8 wfrag = *(const bf16x8*)&wfA[1][((ct * 8 + ks2) * 64 + l) * 8];
            acc2[ct] = __builtin_amdgcn_mfma_f32_32x32x16_bf16(wfrag, bb.v, acc2[ct], 0, 0, 0);
        }
    }

    // ---- epilogue: partial dot over own 64 n2, combine across lane pair ----
    float pq = 0.f, pk = 0.f;
#pragma unroll
    for (int ct = 0; ct < 4; ct++) {
#pragma unroll
        for (int g = 0; g < 4; g++) {
            float4 b2v = *(const float4*)&cv[128 + 32 * ct + 8 * g + 4 * hi];
            float4 wqv = *(const float4*)&cv[256 + 32 * ct + 8 * g + 4 * hi];
            float4 wkv = *(const float4*)&cv[384 + 32 * ct + 8 * g + 4 * hi];
            const float* b2a = (const float*)&b2v;
            const float* wqa = (const float*)&wqv;
            const float* wka = (const float*)&wkv;
#pragma unroll
            for (int i = 0; i < 4; i++) {
                float hv = fmaxf(acc2[ct][4 * g + i] + b2a[i], 0.f);
                pq = fmaf(hv, wqa[i], pq);
                pk = fmaf(hv, wka[i], pk);
            }
        }
    }
    pq += __shfl_xor(pq, 32, 64);
    pk += __shfl_xor(pk, 32, 64);
    if (hi == 0 && node < N) tab[node] = pack2(pq, pk);
}

// ---------------------------------------------------------------------------
// Edge pass: 4 edges/thread (int4/float4), async LDS table staging overlapped
// with the table-independent cast outputs; indices carried across the barrier.
// ---------------------------------------------------------------------------
__global__ __launch_bounds__(1024) void edge_kernel(
    const int* __restrict__ eip, const int* __restrict__ ein,
    const unsigned* __restrict__ tab, const float* __restrict__ be_p,
    float* __restrict__ out, int E)
{
    __shared__ __align__(16) unsigned lt[LIM];   // 163840 B
    const int tid = threadIdx.x;
    const int wv = tid >> 6, ln = tid & 63;

    // ---- issue async staging DMA: 10240 uint4, 16 waves x 10 iters ----
    const uint4* tg4 = (const uint4*)tab;
#pragma unroll
    for (int t = 0; t < LIM / 4 / 1024; t++) {
        int c = (t * 16 + wv) * 64;
        __builtin_amdgcn_global_load_lds(
            (const __attribute__((address_space(1))) void*)(tg4 + c + ln),
            (__attribute__((address_space(3))) void*)((char*)lt + (size_t)c * 16),
            16, 0, 0);
    }
    __builtin_amdgcn_sched_barrier(0);

    const int U = E >> 2;                         // 4-edge units (E % 4 == 0)
    const int chunk = (U + gridDim.x - 1) / gridDim.x;
    const int ustart = blockIdx.x * chunk;
    const int uend = min(U, ustart + chunk);

    const int4* eip4 = (const int4*)eip;
    const int4* ein4 = (const int4*)ein;
    float4* out4 = (float4*)out;

    // ---- phase A: cast outputs (overlaps DMA); keep indices in registers ----
    const int u0 = ustart + tid, u1 = u0 + 1024;
    const bool v0 = u0 < uend, v1 = u1 < uend;
    int4 ns0 = {0,0,0,0}, nd0 = {0,0,0,0}, ns1 = {0,0,0,0}, nd1 = {0,0,0,0};
    if (v0) {
        ns0 = ein4[u0]; nd0 = ein4[U + u0];
        out4[2 * U + u0] = make_float4((float)ns0.x, (float)ns0.y, (float)ns0.z, (float)ns0.w);
        out4[3 * U + u0] = make_float4((float)nd0.x, (float)nd0.y, (float)nd0.z, (float)nd0.w);
    }
    if (v1) {
        ns1 = ein4[u1]; nd1 = ein4[U + u1];
        out4[2 * U + u1] = make_float4((float)ns1.x, (float)ns1.y, (float)ns1.z, (float)ns1.w);
        out4[3 * U + u1] = make_float4((float)nd1.x, (float)nd1.y, (float)nd1.z, (float)nd1.w);
    }
    __syncthreads();   // drains DMA (vmcnt) + makes lt visible

    const float be = be_p[0];
#define GATHER(i) ((i) < LIM ? lt[i] : tab[i])
#define SCORE(us, ud) (__uint_as_float((us) << 16) + __uint_as_float((ud) & 0xFFFF0000u) + be)

    // ---- phase B: score outputs ----
    if (v0) {
        int4 ps = eip4[u0], pd = eip4[U + u0];
        unsigned a0 = GATHER(ps.x), a1 = GATHER(ps.y), a2 = GATHER(ps.z), a3 = GATHER(ps.w);
        unsigned b0 = GATHER(pd.x), b1 = GATHER(pd.y), b2 = GATHER(pd.z), b3 = GATHER(pd.w);
        unsigned c0 = GATHER(ns0.x), c1 = GATHER(ns0.y), c2 = GATHER(ns0.z), c3 = GATHER(ns0.w);
        unsigned d0 = GATHER(nd0.x), d1 = GATHER(nd0.y), d2 = GATHER(nd0.z), d3 = GATHER(nd0.w);
        out4[u0]     = make_float4(SCORE(a0,b0), SCORE(a1,b1), SCORE(a2,b2), SCORE(a3,b3));
        out4[U + u0] = make_float4(SCORE(c0,d0), SCORE(c1,d1), SCORE(c2,d2), SCORE(c3,d3));
    }
    if (v1) {
        int4 ps = eip4[u1], pd = eip4[U + u1];
        unsigned a0 = GATHER(ps.x), a1 = GATHER(ps.y), a2 = GATHER(ps.z), a3 = GATHER(ps.w);
        unsigned b0 = GATHER(pd.x), b1 = GATHER(pd.y), b2 = GATHER(pd.z), b3 = GATHER(pd.w);
        unsigned c0 = GATHER(ns1.x), c1 = GATHER(ns1.y), c2 = GATHER(ns1.z), c3 = GATHER(ns1.w);
        unsigned d0 = GATHER(nd1.x), d1 = GATHER(nd1.y), d2 = GATHER(nd1.z), d3 = GATHER(nd1.w);
        out4[u1]     = make_float4(SCORE(a0,b0), SCORE(a1,b1), SCORE(a2,b2), SCORE(a3,b3));
        out4[U + u1] = make_float4(SCORE(c0,d0), SCORE(c1,d1), SCORE(c2,d2), SCORE(c3,d3));
    }
#undef GATHER
#undef SCORE
}

extern "C" void kernel_launch(void* const* d_in, const int* in_sizes, int n_in,
                              void* d_out, int out_size, void* d_ws, size_t ws_size,
                              hipStream_t stream) {
    const float* x   = (const float*)d_in[0];
    const int*   eip = (const int*)d_in[1];
    const int*   ein = (const int*)d_in[2];
    // d_in[3] = batch (unused)
    const float* W1  = (const float*)d_in[4];
    const float* b1  = (const float*)d_in[5];
    const float* W2  = (const float*)d_in[6];
    const float* b2  = (const float*)d_in[7];
    const float* We  = (const float*)d_in[8];
    const float* be  = (const float*)d_in[9];

    const int N = in_sizes[0] / CDIM;
    const int E = in_sizes[1] / 2;

    // workspace: [0, 200704) packed bf16x2 score table; then fragment-linear W
    char* ws = (char*)d_ws;
    unsigned* tab = (unsigned*)ws;                   // N*4 B
    short*    wf1 = (short*)(ws + 200704);           // 32768 B
    short*    wf2 = (short*)(ws + 200704 + 32768);   // 32768 B

    prep_kernel<<<128, 256, 0, stream>>>(W1, W2, wf1, wf2);
    node_mfma<<<(N + 127) / 128, 256, 0, stream>>>(x, wf1, b1, wf2, b2, We, tab, N);
    edge_kernel<<<256, 1024, 0, stream>>>(eip, ein, tab, be, (float*)d_out, E);
}